// Round 3
// baseline (190.699 us; speedup 1.0000x reference)
//
#include <hip/hip_runtime.h>

// CRF forward (logZ) — B=1024 chains, T=256 steps, N=64 labels.
// TWO chains per 64-lane wave, register-interleaved; lane k owns label k.
//   Rationale: with 1024 waves on 1024 SIMDs the kernel is latency-bound
//   (VALUBusy 48%, step = 562 cyc vs ~270 issue). Packing waves/SIMD is
//   neutral (#waves == #SIMDs), so instead each wave carries 2 independent
//   recurrences — the second chain's instructions fill the first chain's
//   dependency/hazard stalls inside one instruction stream. Epk (32 VGPRs)
//   is shared; per-chain state is ~30 VGPRs (1 wave/SIMD, no occupancy cost).
// Inner dot in bf16 pairs:  s_k = sum_m dot2(u_pair[m], E_pair[m][k])
//   32 readlanes + 32 v_dot2_f32_bf16 (f32 accum) per chain-step.
// Pair runs to max(lenA,lenB) with wave-uniform freeze predication
// (u/R/Pm frozen once t >= len — identical algebra to stopping at len).
// Exact lse recursion with per-step scaling; only dot INPUTS are bf16.

#define CRF_B 1024
#define CRF_T 256
#define CRF_N 64

typedef __bf16 bf16x2 __attribute__((ext_vector_type(2)));

__device__ __forceinline__ float rl0(float x) {
    return __int_as_float(__builtin_amdgcn_readfirstlane(__float_as_int(x)));
}
__device__ __forceinline__ float rlanef(float x, int j) {
    return __int_as_float(__builtin_amdgcn_readlane(__float_as_int(x), j));
}

__device__ __forceinline__ float wave_lse(float v) {
    float m = v;
    #pragma unroll
    for (int off = 1; off < 64; off <<= 1) m = fmaxf(m, __shfl_xor(m, off));
    float s = __expf(v - m);
    #pragma unroll
    for (int off = 1; off < 64; off <<= 1) s += __shfl_xor(s, off);
    return m + __logf(s);
}

// f32 -> bf16 (round-to-nearest-even), low 16 bits of result
__device__ __forceinline__ unsigned bf16_rne(float f) {
    unsigned u = __float_as_uint(f);
    return (u + 0x7FFFu + ((u >> 16) & 1u)) >> 16;
}

// lane L: pack(bf16(u_L), bf16(u_{L^1})) — valid pairs read from EVEN lanes
__device__ __forceinline__ unsigned pack_pairs(float u) {
    unsigned pa = __float_as_uint(u) + 0x8000u;                 // cheap RN
    unsigned pb = (unsigned)__builtin_amdgcn_update_dpp(
        0, (int)pa, 0xB1 /*quad_perm [1,0,3,2]*/, 0xF, 0xF, false);
    // result: lo16 = pa[31:16], hi16 = pb[31:16]
    return __builtin_amdgcn_perm(pb, pa, 0x07060302);
}

__device__ __forceinline__ float dot2bf(unsigned a, unsigned b, float c) {
#if __has_builtin(__builtin_amdgcn_fdot2_f32_bf16)
    return __builtin_amdgcn_fdot2_f32_bf16(__builtin_bit_cast(bf16x2, a),
                                           __builtin_bit_cast(bf16x2, b),
                                           c, false);
#else
    float d = c;
    asm("v_dot2_f32_bf16 %0, %1, %2, %0" : "+v"(d) : "v"(a), "v"(b));
    return d;
#endif
}

// ---- sequence length from mask (dtype-adaptive: bool bytes vs int32) ----
__device__ __forceinline__ int seq_len(const unsigned char* __restrict__ mask_u8,
                                       int b, int lane) {
    int c8 = 0;
    #pragma unroll
    for (int q = 0; q < 4; ++q)
        c8 += (mask_u8[(size_t)b * CRF_T + q * 64 + lane] != 0) ? 1 : 0;
    #pragma unroll
    for (int off = 1; off < 64; off <<= 1) c8 += __shfl_xor(c8, off);
    if (c8 >= 128) return c8;          // genuine bool bytes (len in [128,256])
    const int* mi = (const int*)mask_u8;
    int ci = 0;
    #pragma unroll
    for (int q = 0; q < 4; ++q)
        ci += (mi[(size_t)b * CRF_T + q * 64 + lane] != 0) ? 1 : 0;
    #pragma unroll
    for (int off = 1; off < 64; off <<= 1) ci += __shfl_xor(ci, off);
    return ci;
}

__launch_bounds__(64, 1)
__global__ void crf_fwd_kernel(const float* __restrict__ emit,
                               const float* __restrict__ trans,
                               const float* __restrict__ strans,
                               const float* __restrict__ etrans,
                               const unsigned char* __restrict__ mask_u8,
                               float* __restrict__ out)
{
    const int lane = threadIdx.x;            // 0..63
    const int bA   = blockIdx.x * 2;         // chain pair
    const int bB   = bA + 1;

    // ---------- register-only preprocess (per wave, chain-invariant) ----------
    float rowlse_v;
    {
        const float* rowp = trans + lane * CRF_N;
        float m = -1e30f;
        #pragma unroll 8
        for (int k = 0; k < CRF_N; ++k) m = fmaxf(m, rowp[k]);
        float s = 0.f;
        #pragma unroll 8
        for (int k = 0; k < CRF_N; ++k) s += __expf(rowp[k] - m);
        rowlse_v = m + __logf(s);
    }

    // pass 1: column max of tn (for this lane's label)
    float cmx = -1e30f;
    #pragma unroll
    for (int j = 0; j < CRF_N; ++j)
        cmx = fmaxf(cmx, trans[j * CRF_N + lane] - rlanef(rowlse_v, j));

    // pass 2: packed bf16 E pairs — Epk[m] = (E[2m][lane], E[2m+1][lane])
    unsigned Epk[32];
    #pragma unroll
    for (int m = 0; m < 32; ++m) {
        float e0 = __expf(trans[(2 * m)     * CRF_N + lane] - rlanef(rowlse_v, 2 * m)     - cmx);
        float e1 = __expf(trans[(2 * m + 1) * CRF_N + lane] - rlanef(rowlse_v, 2 * m + 1) - cmx);
        Epk[m] = bf16_rne(e0) | (bf16_rne(e1) << 16);
    }

    const float sn = wave_lse(strans[lane]);

    const int lenA = seq_len(mask_u8, bA, lane);
    const int lenB = seq_len(mask_u8, bB, lane);
    const int lenMax = (lenA > lenB) ? lenA : lenB;

    const float* ebA = emit + (size_t)bA * CRF_T * CRF_N;
    const float* ebB = emit + (size_t)bB * CRF_T * CRF_N;

    // ---------- init (t = 0), per chain ----------
    float alpha0A = (strans[lane] - sn) + ebA[lane];
    float alpha0B = (strans[lane] - sn) + ebB[lane];
    float c0A = rl0(alpha0A), c0B = rl0(alpha0B);
    float uA = __expf(alpha0A - c0A);      // lane 0: u = 1
    float uB = __expf(alpha0B - c0B);
    unsigned upiA = pack_pairs(uA);
    unsigned upiB = pack_pairs(uB);
    float RA = 1.0f, RB = 1.0f;            // rcp of previous step's u0
    float PmA = 1.0f, PmB = 1.0f;          // running product of u0 (mantissa)
    int   EaccA = 0, EaccB = 0;            // running exponent (base 2)

    // one chain-step (SFX = A or B); LIVE is wave-uniform.
#define CRF_STEP(SFX, EE, EE0, LIVE)                                        \
    {                                                                       \
        float ree = R##SFX * (EE);        /* ready before dot completes */  \
        float sc0 = R##SFX * (EE0);                                         \
        float a0 = 0.f, a1 = 0.f, a2 = 0.f, a3 = 0.f;                       \
        _Pragma("unroll")                                                   \
        for (int m2 = 0; m2 < 32; m2 += 4) {                                \
            unsigned w0 = (unsigned)__builtin_amdgcn_readlane((int)upi##SFX, 2 * m2 + 0); \
            unsigned w1 = (unsigned)__builtin_amdgcn_readlane((int)upi##SFX, 2 * m2 + 2); \
            unsigned w2 = (unsigned)__builtin_amdgcn_readlane((int)upi##SFX, 2 * m2 + 4); \
            unsigned w3 = (unsigned)__builtin_amdgcn_readlane((int)upi##SFX, 2 * m2 + 6); \
            a0 = dot2bf(w0, Epk[m2 + 0], a0);                               \
            a1 = dot2bf(w1, Epk[m2 + 1], a1);                               \
            a2 = dot2bf(w2, Epk[m2 + 2], a2);                               \
            a3 = dot2bf(w3, Epk[m2 + 3], a3);                               \
        }                                                                   \
        float s = (a0 + a1) + (a2 + a3);                                    \
        float s0 = rl0(s);                                                  \
        float u0 = s0 * sc0;              /* == lane-0 of new u */          \
        const bool lv_ = (LIVE);                                            \
        u##SFX  = lv_ ? (s * ree) : u##SFX;                                 \
        R##SFX  = lv_ ? __builtin_amdgcn_rcpf(u0) : R##SFX;                 \
        Pm##SFX *= lv_ ? u0 : 1.0f;                                         \
        upi##SFX = pack_pairs(u##SFX);                                      \
    }

    // ---------- main loop: groups of 4 with emission prefetch ----------
    float eNA[4], eeCA[4], ee0CA[4];
    float eNB[4], eeCB[4], ee0CB[4];
    #pragma unroll
    for (int d = 0; d < 4; ++d) {
        eNA[d] = ebA[(size_t)(1 + d) * CRF_N + lane];
        eNB[d] = ebB[(size_t)(1 + d) * CRF_N + lane];
    }
    #pragma unroll
    for (int d = 0; d < 4; ++d) { eeCA[d] = __expf(eNA[d] + cmx); eeCB[d] = __expf(eNB[d] + cmx); }
    #pragma unroll
    for (int d = 0; d < 4; ++d) { ee0CA[d] = rl0(eeCA[d]); ee0CB[d] = rl0(eeCB[d]); }

    int t0 = 1;
    while (t0 + 4 <= lenMax) {
        #pragma unroll
        for (int d = 0; d < 4; ++d) {
            int tiA = t0 + 4 + d; tiA = (tiA < lenA) ? tiA : (lenA - 1);
            eNA[d] = ebA[(size_t)tiA * CRF_N + lane];
            int tiB = t0 + 4 + d; tiB = (tiB < lenB) ? tiB : (lenB - 1);
            eNB[d] = ebB[(size_t)tiB * CRF_N + lane];
        }
        CRF_STEP(A, eeCA[0], ee0CA[0], t0 + 0 < lenA);
        CRF_STEP(B, eeCB[0], ee0CB[0], t0 + 0 < lenB);
        CRF_STEP(A, eeCA[1], ee0CA[1], t0 + 1 < lenA);
        CRF_STEP(B, eeCB[1], ee0CB[1], t0 + 1 < lenB);
        CRF_STEP(A, eeCA[2], ee0CA[2], t0 + 2 < lenA);
        CRF_STEP(B, eeCB[2], ee0CB[2], t0 + 2 < lenB);
        CRF_STEP(A, eeCA[3], ee0CA[3], t0 + 3 < lenA);
        CRF_STEP(B, eeCB[3], ee0CB[3], t0 + 3 < lenB);
        {
            int ex;
            PmA = frexpf(PmA, &ex); EaccA += ex;
            PmB = frexpf(PmB, &ex); EaccB += ex;
        }
        #pragma unroll
        for (int d = 0; d < 4; ++d) { eeCA[d] = __expf(eNA[d] + cmx); eeCB[d] = __expf(eNB[d] + cmx); }
        #pragma unroll
        for (int d = 0; d < 4; ++d) { ee0CA[d] = rl0(eeCA[d]); ee0CB[d] = rl0(eeCB[d]); }
        t0 += 4;
    }
    {
        const int nrem = lenMax - t0;   // wave-uniform, < 4
        #pragma unroll
        for (int d = 0; d < 4; ++d) {
            if (d >= nrem) break;
            CRF_STEP(A, eeCA[d], ee0CA[d], t0 + d < lenA);
            CRF_STEP(B, eeCB[d], ee0CB[d], t0 + d < lenB);
        }
    }
#undef CRF_STEP

    // ---------- final lse over labels + batch-sum (both chains) ----------
    const float en = wave_lse(etrans[lane]);
    float z = 0.f;
    {
        float Lacc = c0A + 0.6931471805599453f * (float)EaccA + __logf(PmA);
        float v = Lacc + __logf(uA * RA) + (etrans[lane] - en);
        float m = v;
        #pragma unroll
        for (int off = 1; off < 64; off <<= 1) m = fmaxf(m, __shfl_xor(m, off));
        float sum = __expf(v - m);
        #pragma unroll
        for (int off = 1; off < 64; off <<= 1) sum += __shfl_xor(sum, off);
        z += m + __logf(sum);
    }
    {
        float Lacc = c0B + 0.6931471805599453f * (float)EaccB + __logf(PmB);
        float v = Lacc + __logf(uB * RB) + (etrans[lane] - en);
        float m = v;
        #pragma unroll
        for (int off = 1; off < 64; off <<= 1) m = fmaxf(m, __shfl_xor(m, off));
        float sum = __expf(v - m);
        #pragma unroll
        for (int off = 1; off < 64; off <<= 1) sum += __shfl_xor(sum, off);
        z += m + __logf(sum);
    }

    if (lane == 0) {
        atomicAdd(out, z);
    }
}

extern "C" void kernel_launch(void* const* d_in, const int* in_sizes, int n_in,
                              void* d_out, int out_size, void* d_ws, size_t ws_size,
                              hipStream_t stream) {
    const float* emit   = (const float*)d_in[0];
    const float* trans  = (const float*)d_in[1];
    const float* strans = (const float*)d_in[2];
    const float* etrans = (const float*)d_in[3];
    const unsigned char* mask = (const unsigned char*)d_in[4];
    float* out = (float*)d_out;

    hipMemsetAsync(out, 0, sizeof(float), stream);
    crf_fwd_kernel<<<dim3(CRF_B / 2), dim3(64), 0, stream>>>(
        emit, trans, strans, etrans, mask, out);
}

// Round 4
// 144.466 us; speedup vs baseline: 1.3200x; 1.3200x over previous
//
#include <hip/hip_runtime.h>

// CRF forward (logZ) — B=1024 chains, T=256 steps, N=64 labels.
// One 64-lane wave per chain; lane k owns label k.
// Broadcast of u across lanes via LDS (not v_readlane):
//   end of step:  lane k writes bf16(u_k) -> s_up (ds_write_b16, 2 lanes/bank = free)
//   next step:    8x ds_read_b128 at wave-uniform addr (pure broadcast) -> 32 dot2
//   dot operands are VGPRs -> no VALU->SGPR->VALU hazard wait-states
//   (R3 showed those hazards are per-wave pipeline stalls the compiler
//    cannot schedule around: in-wave 2-chain interleave filled only 9%).
// Same-wave LDS ordering: DS ops execute in issue order; the write's data
// depends on all reads' results, so RAW/WAR are structurally safe (no barrier).
// Inner dot in bf16 pairs: s_k = sum_m dot2(u_pair[m], E_pair[m][k]), f32 accum.
//   u_k(t) = s_k * (R(t-1)*ee_k(t)); R = rcp(u0), Pm *= u0 on the f32 side chain
//   with u0 = rl0(s)*R*ee0 (off the broadcast critical path).
// Exact lse recursion with per-step scaling; only dot INPUTS are bf16
// (identical rounding to the verified baseline: (bits+0x8000)>>16).

#define CRF_B 1024
#define CRF_T 256
#define CRF_N 64

typedef __bf16 bf16x2 __attribute__((ext_vector_type(2)));

__device__ __forceinline__ float rl0(float x) {
    return __int_as_float(__builtin_amdgcn_readfirstlane(__float_as_int(x)));
}
__device__ __forceinline__ float rlanef(float x, int j) {
    return __int_as_float(__builtin_amdgcn_readlane(__float_as_int(x), j));
}

__device__ __forceinline__ float wave_lse(float v) {
    float m = v;
    #pragma unroll
    for (int off = 1; off < 64; off <<= 1) m = fmaxf(m, __shfl_xor(m, off));
    float s = __expf(v - m);
    #pragma unroll
    for (int off = 1; off < 64; off <<= 1) s += __shfl_xor(s, off);
    return m + __logf(s);
}

// f32 -> bf16 (round-to-nearest-even), low 16 bits of result
__device__ __forceinline__ unsigned bf16_rne(float f) {
    unsigned u = __float_as_uint(f);
    return (u + 0x7FFFu + ((u >> 16) & 1u)) >> 16;
}

__device__ __forceinline__ float dot2bf(unsigned a, unsigned b, float c) {
#if __has_builtin(__builtin_amdgcn_fdot2_f32_bf16)
    return __builtin_amdgcn_fdot2_f32_bf16(__builtin_bit_cast(bf16x2, a),
                                           __builtin_bit_cast(bf16x2, b),
                                           c, false);
#else
    float d = c;
    asm("v_dot2_f32_bf16 %0, %1, %2, %0" : "+v"(d) : "v"(a), "v"(b));
    return d;
#endif
}

__launch_bounds__(64, 1)
__global__ void crf_fwd_kernel(const float* __restrict__ emit,
                               const float* __restrict__ trans,
                               const float* __restrict__ strans,
                               const float* __restrict__ etrans,
                               const unsigned char* __restrict__ mask_u8,
                               float* __restrict__ out)
{
    const int lane = threadIdx.x;   // 0..63
    const int b    = blockIdx.x;

    // 64 bf16 u-values, packed as 32 dwords of (u_2m, u_2m+1) pairs.
    __shared__ __attribute__((aligned(16))) unsigned s_up[32];

    // ---------- register-only preprocess (per wave) ----------
    float rowlse_v;
    {
        const float* rowp = trans + lane * CRF_N;
        float m = -1e30f;
        #pragma unroll 8
        for (int k = 0; k < CRF_N; ++k) m = fmaxf(m, rowp[k]);
        float s = 0.f;
        #pragma unroll 8
        for (int k = 0; k < CRF_N; ++k) s += __expf(rowp[k] - m);
        rowlse_v = m + __logf(s);
    }

    // pass 1: column max of tn (for this lane's label)
    float cmx = -1e30f;
    #pragma unroll
    for (int j = 0; j < CRF_N; ++j)
        cmx = fmaxf(cmx, trans[j * CRF_N + lane] - rlanef(rowlse_v, j));

    // pass 2: packed bf16 E pairs — Epk[m] = (E[2m][lane], E[2m+1][lane])
    unsigned Epk[32];
    #pragma unroll
    for (int m = 0; m < 32; ++m) {
        float e0 = __expf(trans[(2 * m)     * CRF_N + lane] - rlanef(rowlse_v, 2 * m)     - cmx);
        float e1 = __expf(trans[(2 * m + 1) * CRF_N + lane] - rlanef(rowlse_v, 2 * m + 1) - cmx);
        Epk[m] = bf16_rne(e0) | (bf16_rne(e1) << 16);
    }

    const float sn = wave_lse(strans[lane]);

    // ---- sequence length from mask (dtype-adaptive: bool bytes vs int32) ----
    int len;
    {
        int c8 = 0;
        #pragma unroll
        for (int q = 0; q < 4; ++q)
            c8 += (mask_u8[(size_t)b * CRF_T + q * 64 + lane] != 0) ? 1 : 0;
        for (int off = 1; off < 64; off <<= 1) c8 += __shfl_xor(c8, off);
        if (c8 >= 128) {
            len = c8;       // genuine bool bytes (len in [128,256])
        } else {
            const int* mi = (const int*)mask_u8;
            int ci = 0;
            #pragma unroll
            for (int q = 0; q < 4; ++q)
                ci += (mi[(size_t)b * CRF_T + q * 64 + lane] != 0) ? 1 : 0;
            for (int off = 1; off < 64; off <<= 1) ci += __shfl_xor(ci, off);
            len = ci;
        }
    }

    const float* eb = emit + (size_t)b * CRF_T * CRF_N;

    // ---------- init (t = 0) ----------
    float alpha0 = (strans[lane] - sn) + eb[lane];
    float c0 = rl0(alpha0);
    float u  = __expf(alpha0 - c0);   // lane 0: u = 1
    // publish bf16(u) for the first step's broadcast (same rounding as baseline)
    ((unsigned short*)s_up)[lane] =
        (unsigned short)((__float_as_uint(u) + 0x8000u) >> 16);
    float R  = 1.0f;                  // rcp of previous step's u0
    float Pm = 1.0f;                  // running product of u0 (mantissa)
    int   Eacc = 0;                   // running exponent (base 2)

    // one step: LDS-broadcast dots, then publish new u
#define CRF_STEP(EE, EE0)                                                   \
    {                                                                       \
        float ree = R * (EE);         /* ready before dot completes */      \
        float sc0 = R * (EE0);                                              \
        float a0 = 0.f, a1 = 0.f, a2 = 0.f, a3 = 0.f;                       \
        _Pragma("unroll")                                                   \
        for (int m2 = 0; m2 < 32; m2 += 4) {                                \
            uint4 w = *(const uint4*)&s_up[m2];   /* ds_read_b128 bcast */  \
            a0 = dot2bf(w.x, Epk[m2 + 0], a0);                              \
            a1 = dot2bf(w.y, Epk[m2 + 1], a1);                              \
            a2 = dot2bf(w.z, Epk[m2 + 2], a2);                              \
            a3 = dot2bf(w.w, Epk[m2 + 3], a3);                              \
        }                                                                   \
        float s = (a0 + a1) + (a2 + a3);                                    \
        float s0 = rl0(s);                                                  \
        u = s * ree;                                                        \
        ((unsigned short*)s_up)[lane] =                                     \
            (unsigned short)((__float_as_uint(u) + 0x8000u) >> 16);         \
        float u0 = s0 * sc0;          /* == lane-0 of u (assoc. diff) */    \
        R = __builtin_amdgcn_rcpf(u0);                                      \
        Pm *= u0;                                                           \
    }

    // ---------- main loop: groups of 4 with emission prefetch ----------
    float eN[4], eeC[4], ee0C[4];
    #pragma unroll
    for (int d = 0; d < 4; ++d) eN[d] = eb[(size_t)(1 + d) * CRF_N + lane];
    #pragma unroll
    for (int d = 0; d < 4; ++d) eeC[d] = __expf(eN[d] + cmx);
    #pragma unroll
    for (int d = 0; d < 4; ++d) ee0C[d] = rl0(eeC[d]);

    int t0 = 1;
    while (t0 + 4 <= len) {
        #pragma unroll
        for (int d = 0; d < 4; ++d) {
            int ti = t0 + 4 + d;
            ti = (ti < len) ? ti : (len - 1);
            eN[d] = eb[(size_t)ti * CRF_N + lane];
        }
        CRF_STEP(eeC[0], ee0C[0]); CRF_STEP(eeC[1], ee0C[1]);
        CRF_STEP(eeC[2], ee0C[2]); CRF_STEP(eeC[3], ee0C[3]);
        {
            int ex;
            Pm = frexpf(Pm, &ex);
            Eacc += ex;
        }
        #pragma unroll
        for (int d = 0; d < 4; ++d) eeC[d] = __expf(eN[d] + cmx);
        #pragma unroll
        for (int d = 0; d < 4; ++d) ee0C[d] = rl0(eeC[d]);
        t0 += 4;
    }
    {
        const int nrem = len - t0;   // wave-uniform, < 4
        #pragma unroll
        for (int d = 0; d < 4; ++d) {
            if (d >= nrem) break;
            CRF_STEP(eeC[d], ee0C[d]);
        }
    }
#undef CRF_STEP

    // ---------- final lse over labels + batch-sum ----------
    const float en = wave_lse(etrans[lane]);
    float Lacc = c0 + 0.6931471805599453f * (float)Eacc + __logf(Pm);
    float v = Lacc + __logf(u * R) + (etrans[lane] - en);
    float m = v;
    #pragma unroll
    for (int off = 1; off < 64; off <<= 1) m = fmaxf(m, __shfl_xor(m, off));
    float sum = __expf(v - m);
    #pragma unroll
    for (int off = 1; off < 64; off <<= 1) sum += __shfl_xor(sum, off);

    if (lane == 0) {
        atomicAdd(out, m + __logf(sum));
    }
}

extern "C" void kernel_launch(void* const* d_in, const int* in_sizes, int n_in,
                              void* d_out, int out_size, void* d_ws, size_t ws_size,
                              hipStream_t stream) {
    const float* emit   = (const float*)d_in[0];
    const float* trans  = (const float*)d_in[1];
    const float* strans = (const float*)d_in[2];
    const float* etrans = (const float*)d_in[3];
    const unsigned char* mask = (const unsigned char*)d_in[4];
    float* out = (float*)d_out;

    hipMemsetAsync(out, 0, sizeof(float), stream);
    crf_fwd_kernel<<<dim3(CRF_B), dim3(64), 0, stream>>>(
        emit, trans, strans, etrans, mask, out);
}